// Round 1
// baseline (1579.423 us; speedup 1.0000x reference)
//
#include <hip/hip_runtime.h>

#define NS_ 100000
#define NW_ 400000
#define NE_ 500000

__device__ __forceinline__ float lrelu02(float x) { return x > 0.f ? x : 0.2f * x; }

// ---------------------------------------------------------------------------
// A: xs = x_sites @ W_sw  ([NS,256]) and al_s[n,h] = xs[n,h,:]·att_src[h,:]
// One block = 32 sites; thread j owns output column j (W column in 64 VGPRs).
// ---------------------------------------------------------------------------
__global__ void __launch_bounds__(256)
k_sites_pre(const float* __restrict__ x_sites, const float* __restrict__ W_sw,
            const float* __restrict__ att_src, float* __restrict__ xs,
            float* __restrict__ al_s)
{
    __shared__ float xlds[32][68];
    const int tid = threadIdx.x;
    float w[64];
#pragma unroll
    for (int d = 0; d < 64; ++d) w[d] = W_sw[d * 256 + tid];
    const float att = att_src[tid];   // att flat [4*64], head = tid>>6
    const int base = blockIdx.x * 32;
    for (int i = tid; i < 32 * 64; i += 256) {
        int s = i >> 6, d = i & 63;
        xlds[s][d] = x_sites[(size_t)(base + s) * 64 + d];
    }
    __syncthreads();
    const int head = tid >> 6, lane = tid & 63;
    for (int s = 0; s < 32; ++s) {
        const float4* xr = (const float4*)(&xlds[s][0]);   // row stride 272B, 16B aligned
        float acc = 0.f;
#pragma unroll
        for (int d4 = 0; d4 < 16; ++d4) {
            float4 xv = xr[d4];
            acc += xv.x * w[4 * d4] + xv.y * w[4 * d4 + 1] + xv.z * w[4 * d4 + 2] + xv.w * w[4 * d4 + 3];
        }
        xs[(size_t)(base + s) * 256 + tid] = acc;
        float p = acc * att;
#pragma unroll
        for (int off = 32; off > 0; off >>= 1) p += __shfl_down(p, off, 64);
        if (lane == 0) al_s[(size_t)(base + s) * 4 + head] = p;
    }
}

// ---------------------------------------------------------------------------
// B: al_d = x_wells @ v_d, v_d[d,h] = sum_c W_sw[d,h*64+c]*att_dst[h,c]
// One block = 64 wells.
// ---------------------------------------------------------------------------
__global__ void __launch_bounds__(256)
k_wells_pre(const float* __restrict__ x_wells, const float* __restrict__ W_sw,
            const float* __restrict__ att_dst, float* __restrict__ al_d)
{
    __shared__ float vd[64][4];
    __shared__ float xlds[64][68];
    const int tid = threadIdx.x;
    {
        int d = tid >> 2, h = tid & 3;
        const float4* wp = (const float4*)(W_sw + d * 256 + h * 64);
        const float4* ap = (const float4*)(att_dst + h * 64);
        float acc = 0.f;
#pragma unroll
        for (int c = 0; c < 16; ++c) {
            float4 wv = wp[c]; float4 av = ap[c];
            acc += wv.x * av.x + wv.y * av.y + wv.z * av.z + wv.w * av.w;
        }
        vd[d][h] = acc;
    }
    const int base = blockIdx.x * 64;
    for (int i = tid; i < 64 * 64; i += 256) {
        int wl = i >> 6, d = i & 63;
        xlds[wl][d] = x_wells[(size_t)(base + wl) * 64 + d];
    }
    __syncthreads();
    const int wl = tid >> 2, h = tid & 3;
    float acc = 0.f;
#pragma unroll
    for (int d = 0; d < 64; ++d) acc += xlds[wl][d] * vd[d][h];
    al_d[(size_t)(base + wl) * 4 + h] = acc;   // tid-coalesced
}

// ---------------------------------------------------------------------------
// C: denom[w,h] += exp(lrelu(al_s[src]+al_d[dst]))   (no max-shift needed)
// ---------------------------------------------------------------------------
__global__ void __launch_bounds__(256)
k_edge_sw_denom(const int* __restrict__ src, const int* __restrict__ dst,
                const float* __restrict__ al_s, const float* __restrict__ al_d,
                float* __restrict__ denom)
{
    const int e = blockIdx.x * 256 + threadIdx.x;
    if (e >= NE_) return;
    const int s = src[e], w = dst[e];
    float4 as = ((const float4*)al_s)[s];
    float4 ad = ((const float4*)al_d)[w];
    float* dp = denom + (size_t)w * 4;
    unsafeAtomicAdd(dp + 0, __expf(lrelu02(as.x + ad.x)));
    unsafeAtomicAdd(dp + 1, __expf(lrelu02(as.y + ad.y)));
    unsafeAtomicAdd(dp + 2, __expf(lrelu02(as.z + ad.z)));
    unsafeAtomicAdd(dp + 3, __expf(lrelu02(as.w + ad.w)));
}

// ---------------------------------------------------------------------------
// D: gw_acc[w,c] += (1/4) sum_h alpha[e,h] * xs[src,h,c]   (16 lanes/edge)
// ---------------------------------------------------------------------------
__global__ void __launch_bounds__(256)
k_edge_sw_msg(const int* __restrict__ src, const int* __restrict__ dst,
              const float* __restrict__ al_s, const float* __restrict__ al_d,
              const float* __restrict__ denom, const float* __restrict__ xs,
              float* __restrict__ gw_acc)
{
    const int t = blockIdx.x * 256 + threadIdx.x;
    const int e = t >> 4, lane = t & 15;
    if (e >= NE_) return;
    const int s = src[e], w = dst[e];
    float4 as = ((const float4*)al_s)[s];
    float4 ad = ((const float4*)al_d)[w];
    float4 dn = ((const float4*)denom)[w];
    const float a0 = 0.25f * __expf(lrelu02(as.x + ad.x)) / dn.x;
    const float a1 = 0.25f * __expf(lrelu02(as.y + ad.y)) / dn.y;
    const float a2 = 0.25f * __expf(lrelu02(as.z + ad.z)) / dn.z;
    const float a3 = 0.25f * __expf(lrelu02(as.w + ad.w)) / dn.w;
    const float4* xp = (const float4*)(xs + (size_t)s * 256);
    float4 x0 = xp[lane], x1 = xp[16 + lane], x2 = xp[32 + lane], x3 = xp[48 + lane];
    float m0 = a0 * x0.x + a1 * x1.x + a2 * x2.x + a3 * x3.x;
    float m1 = a0 * x0.y + a1 * x1.y + a2 * x2.y + a3 * x3.y;
    float m2 = a0 * x0.z + a1 * x1.z + a2 * x2.z + a3 * x3.z;
    float m3 = a0 * x0.w + a1 * x1.w + a2 * x2.w + a3 * x3.w;
    float* gp = gw_acc + (size_t)w * 64 + lane * 4;
    unsafeAtomicAdd(gp + 0, m0);
    unsafeAtomicAdd(gp + 1, m1);
    unsafeAtomicAdd(gp + 2, m2);
    unsafeAtomicAdd(gp + 3, m3);
}

// ---------------------------------------------------------------------------
// E: SAGE aggregation: ssum[s,:] += x_wells[src,:], cnt[s] += 1
// ---------------------------------------------------------------------------
__global__ void __launch_bounds__(256)
k_edge_ws(const int* __restrict__ src, const int* __restrict__ dst,
          const float* __restrict__ x_wells, float* __restrict__ ssum,
          float* __restrict__ cnt)
{
    const int t = blockIdx.x * 256 + threadIdx.x;
    const int e = t >> 4, lane = t & 15;
    if (e >= NE_) return;
    const int s = src[e], d = dst[e];
    float4 xv = ((const float4*)(x_wells + (size_t)s * 64))[lane];
    float* sp = ssum + (size_t)d * 64 + lane * 4;
    unsafeAtomicAdd(sp + 0, xv.x);
    unsafeAtomicAdd(sp + 1, xv.y);
    unsafeAtomicAdd(sp + 2, xv.z);
    unsafeAtomicAdd(sp + 3, xv.w);
    if (lane == 0) unsafeAtomicAdd(cnt + d, 1.0f);
}

// ---------------------------------------------------------------------------
// F: wells epilogue: t = gw_acc + b_sw + bl_ww + x_wells@(Wl_ww+Wr_ww);
//    out[w] = lrelu_0.01(relu(t)·Wg + bg).   64 wells/block, 4 threads/well.
// ---------------------------------------------------------------------------
__global__ void __launch_bounds__(256)
k_final_wells(const float* __restrict__ x_wells, const float* __restrict__ gw_acc,
              const float* __restrict__ Wl_ww, const float* __restrict__ Wr_ww,
              const float* __restrict__ b_sw, const float* __restrict__ bl_ww,
              const float* __restrict__ Wg, const float* __restrict__ bg,
              float* __restrict__ out)
{
    __shared__ float Wc[64][68];
    __shared__ float xlds[64][68];
    __shared__ float bias[64];
    __shared__ float wg[64];
    const int tid = threadIdx.x;
    for (int i = tid; i < 4096; i += 256) {
        int d = i >> 6, c = i & 63;
        Wc[d][c] = Wl_ww[i] + Wr_ww[i];
    }
    if (tid < 64) { bias[tid] = b_sw[tid] + bl_ww[tid]; wg[tid] = Wg[tid]; }
    const int base = blockIdx.x * 64;
    for (int i = tid; i < 4096; i += 256) {
        int wl = i >> 6, d = i & 63;
        xlds[wl][d] = x_wells[(size_t)(base + wl) * 64 + d];
    }
    __syncthreads();
    const int wl = tid >> 2, p = tid & 3, c0 = p * 16;
    const size_t w = base + wl;
    float t16[16];
    const float4* gp = (const float4*)(gw_acc + w * 64 + c0);
#pragma unroll
    for (int q = 0; q < 4; ++q) {
        float4 g = gp[q];
        t16[4 * q + 0] = g.x + bias[c0 + 4 * q + 0];
        t16[4 * q + 1] = g.y + bias[c0 + 4 * q + 1];
        t16[4 * q + 2] = g.z + bias[c0 + 4 * q + 2];
        t16[4 * q + 3] = g.w + bias[c0 + 4 * q + 3];
    }
#pragma unroll 8
    for (int d = 0; d < 64; ++d) {
        float xv = xlds[wl][d];
        const float4* wr = (const float4*)(&Wc[d][c0]);
#pragma unroll
        for (int q = 0; q < 4; ++q) {
            float4 wv = wr[q];
            t16[4 * q + 0] += xv * wv.x;
            t16[4 * q + 1] += xv * wv.y;
            t16[4 * q + 2] += xv * wv.z;
            t16[4 * q + 3] += xv * wv.w;
        }
    }
    float part = 0.f;
#pragma unroll
    for (int i = 0; i < 16; ++i) {
        float r = t16[i] > 0.f ? t16[i] : 0.f;
        part += r * wg[c0 + i];
    }
    part += __shfl_xor(part, 1, 64);
    part += __shfl_xor(part, 2, 64);
    if (p == 0) {
        float o = part + bg[0];
        out[w] = o > 0.f ? o : 0.01f * o;
    }
}

// ---------------------------------------------------------------------------
// G: sites epilogue: t = (ssum/cnt)@Wl_ws + x@(Wr_ws + mean_h W_ss) + biases;
//    out[NW+s] = lrelu_0.01(relu(t)·Wsit + bsit)
// ---------------------------------------------------------------------------
__global__ void __launch_bounds__(256)
k_final_sites(const float* __restrict__ x_sites, const float* __restrict__ ssum,
              const float* __restrict__ cnt, const float* __restrict__ Wl_ws,
              const float* __restrict__ bl_ws, const float* __restrict__ Wr_ws,
              const float* __restrict__ W_ss, const float* __restrict__ b_ss,
              const float* __restrict__ Wsit, const float* __restrict__ bsit,
              float* __restrict__ out)
{
    __shared__ float Wa[64][68];
    __shared__ float Wb[64][68];
    __shared__ float xlds[64][68];
    __shared__ float mlds[64][68];
    __shared__ float bias[64], wsit[64], rcn[64];
    const int tid = threadIdx.x;
    for (int i = tid; i < 4096; i += 256) {
        int d = i >> 6, c = i & 63;
        Wa[d][c] = Wl_ws[i];
        Wb[d][c] = Wr_ws[i] + 0.25f * (W_ss[d * 256 + c] + W_ss[d * 256 + 64 + c] +
                                       W_ss[d * 256 + 128 + c] + W_ss[d * 256 + 192 + c]);
    }
    const int base = blockIdx.x * 64;
    if (tid < 64) {
        bias[tid] = bl_ws[tid] + b_ss[tid];
        wsit[tid] = Wsit[tid];
        int s = base + tid;
        float c = (s < NS_) ? cnt[s] : 1.f;
        rcn[tid] = 1.f / fmaxf(c, 1.f);
    }
    for (int i = tid; i < 4096; i += 256) {
        int sl = i >> 6, d = i & 63;
        int s = base + sl;
        float xv = 0.f, mv = 0.f;
        if (s < NS_) {
            xv = x_sites[(size_t)s * 64 + d];
            mv = ssum[(size_t)s * 64 + d];
        }
        xlds[sl][d] = xv;
        mlds[sl][d] = mv;
    }
    __syncthreads();
    const int sl = tid >> 2, p = tid & 3, c0 = p * 16;
    const int s = base + sl;
    float ta[16], tb[16];
#pragma unroll
    for (int i = 0; i < 16; ++i) { ta[i] = 0.f; tb[i] = 0.f; }
#pragma unroll 4
    for (int d = 0; d < 64; ++d) {
        float mv = mlds[sl][d];
        float xv = xlds[sl][d];
        const float4* wa = (const float4*)(&Wa[d][c0]);
        const float4* wb = (const float4*)(&Wb[d][c0]);
#pragma unroll
        for (int q = 0; q < 4; ++q) {
            float4 av = wa[q]; float4 bv = wb[q];
            ta[4 * q + 0] += mv * av.x; ta[4 * q + 1] += mv * av.y;
            ta[4 * q + 2] += mv * av.z; ta[4 * q + 3] += mv * av.w;
            tb[4 * q + 0] += xv * bv.x; tb[4 * q + 1] += xv * bv.y;
            tb[4 * q + 2] += xv * bv.z; tb[4 * q + 3] += xv * bv.w;
        }
    }
    const float rc = rcn[sl];
    float part = 0.f;
#pragma unroll
    for (int i = 0; i < 16; ++i) {
        float tv = ta[i] * rc + tb[i] + bias[c0 + i];
        float r = tv > 0.f ? tv : 0.f;
        part += r * wsit[c0 + i];
    }
    part += __shfl_xor(part, 1, 64);
    part += __shfl_xor(part, 2, 64);
    if (p == 0 && s < NS_) {
        float o = part + bsit[0];
        out[(size_t)NW_ + s] = o > 0.f ? o : 0.01f * o;
    }
}

// ---------------------------------------------------------------------------
extern "C" void kernel_launch(void* const* d_in, const int* in_sizes, int n_in,
                              void* d_out, int out_size, void* d_ws, size_t ws_size,
                              hipStream_t stream)
{
    const float* x_sites    = (const float*)d_in[0];
    const float* x_wells    = (const float*)d_in[1];
    const int*   e_sw_src   = (const int*)d_in[2];
    const int*   e_sw_dst   = (const int*)d_in[3];
    const int*   e_ws_src   = (const int*)d_in[4];
    const int*   e_ws_dst   = (const int*)d_in[5];
    const float* W_sw       = (const float*)d_in[6];
    const float* att_src_sw = (const float*)d_in[7];
    const float* att_dst_sw = (const float*)d_in[8];
    const float* b_sw       = (const float*)d_in[9];
    const float* Wl_ws      = (const float*)d_in[10];
    const float* bl_ws      = (const float*)d_in[11];
    const float* Wr_ws      = (const float*)d_in[12];
    const float* W_ss       = (const float*)d_in[13];
    // d_in[14], d_in[15]: att_src_ss / att_dst_ss cancel (single self-edge softmax == 1)
    const float* b_ss       = (const float*)d_in[16];
    const float* Wl_ww      = (const float*)d_in[17];
    const float* bl_ww      = (const float*)d_in[18];
    const float* Wr_ww      = (const float*)d_in[19];
    const float* Wg         = (const float*)d_in[20];
    const float* bg         = (const float*)d_in[21];
    const float* Wsit       = (const float*)d_in[22];
    const float* bsit       = (const float*)d_in[23];
    float* out = (float*)d_out;

    // workspace layout (floats): ~245 MB total
    float* ws    = (float*)d_ws;
    float* xs    = ws;                               // NS*256
    float* al_s  = xs + (size_t)NS_ * 256;           // NS*4
    float* al_d  = al_s + (size_t)NS_ * 4;           // NW*4
    float* denom = al_d + (size_t)NW_ * 4;           // NW*4   (zeroed)
    float* gw    = denom + (size_t)NW_ * 4;          // NW*64  (zeroed)
    float* ssum  = gw + (size_t)NW_ * 64;            // NS*64  (zeroed)
    float* cntp  = ssum + (size_t)NS_ * 64;          // NS     (zeroed)

    const size_t zbytes = ((size_t)NW_ * 4 + (size_t)NW_ * 64 + (size_t)NS_ * 64 + (size_t)NS_) * sizeof(float);
    hipMemsetAsync(denom, 0, zbytes, stream);

    hipLaunchKernelGGL(k_sites_pre, dim3(NS_ / 32), dim3(256), 0, stream,
                       x_sites, W_sw, att_src_sw, xs, al_s);
    hipLaunchKernelGGL(k_wells_pre, dim3(NW_ / 64), dim3(256), 0, stream,
                       x_wells, W_sw, att_dst_sw, al_d);
    hipLaunchKernelGGL(k_edge_sw_denom, dim3((NE_ + 255) / 256), dim3(256), 0, stream,
                       e_sw_src, e_sw_dst, al_s, al_d, denom);
    hipLaunchKernelGGL(k_edge_sw_msg, dim3(NE_ * 16 / 256), dim3(256), 0, stream,
                       e_sw_src, e_sw_dst, al_s, al_d, denom, xs, gw);
    hipLaunchKernelGGL(k_edge_ws, dim3(NE_ * 16 / 256), dim3(256), 0, stream,
                       e_ws_src, e_ws_dst, x_wells, ssum, cntp);
    hipLaunchKernelGGL(k_final_wells, dim3(NW_ / 64), dim3(256), 0, stream,
                       x_wells, gw, Wl_ww, Wr_ww, b_sw, bl_ww, Wg, bg, out);
    hipLaunchKernelGGL(k_final_sites, dim3((NS_ + 63) / 64), dim3(256), 0, stream,
                       x_sites, ssum, cntp, Wl_ws, bl_ws, Wr_ws, W_ss, b_ss, Wsit, bsit, out);
}

// Round 2
// 687.450 us; speedup vs baseline: 2.2975x; 2.2975x over previous
//
#include <hip/hip_runtime.h>

#define NS_ 100000
#define NW_ 400000
#define NE_ 500000
#define EPB 2048   // elements per scan block

__device__ __forceinline__ float lrelu02(float x) { return x > 0.f ? x : 0.2f * x; }

// ---------------------------------------------------------------------------
// xs = x_sites @ W_sw ([NS,256]) and al_s[n,h] = xs[n,h,:]·att_src[h,:]
// ---------------------------------------------------------------------------
__global__ void __launch_bounds__(256)
k_sites_pre(const float* __restrict__ x_sites, const float* __restrict__ W_sw,
            const float* __restrict__ att_src, float* __restrict__ xs,
            float* __restrict__ al_s)
{
    __shared__ float xlds[32][68];
    const int tid = threadIdx.x;
    float w[64];
#pragma unroll
    for (int d = 0; d < 64; ++d) w[d] = W_sw[d * 256 + tid];
    const float att = att_src[tid];
    const int base = blockIdx.x * 32;
    for (int i = tid; i < 32 * 64; i += 256) {
        int s = i >> 6, d = i & 63;
        xlds[s][d] = x_sites[(size_t)(base + s) * 64 + d];
    }
    __syncthreads();
    const int head = tid >> 6, lane = tid & 63;
    for (int s = 0; s < 32; ++s) {
        const float4* xr = (const float4*)(&xlds[s][0]);
        float acc = 0.f;
#pragma unroll
        for (int d4 = 0; d4 < 16; ++d4) {
            float4 xv = xr[d4];
            acc += xv.x * w[4 * d4] + xv.y * w[4 * d4 + 1] + xv.z * w[4 * d4 + 2] + xv.w * w[4 * d4 + 3];
        }
        xs[(size_t)(base + s) * 256 + tid] = acc;
        float p = acc * att;
#pragma unroll
        for (int off = 32; off > 0; off >>= 1) p += __shfl_down(p, off, 64);
        if (lane == 0) al_s[(size_t)(base + s) * 4 + head] = p;
    }
}

// vd[d*4+h] = sum_c W_sw[d, h*64+c] * att_dst[h,c]   (single block)
__global__ void __launch_bounds__(256)
k_vd(const float* __restrict__ W_sw, const float* __restrict__ att_dst,
     float* __restrict__ vd)
{
    const int tid = threadIdx.x;
    const int d = tid >> 2, h = tid & 3;
    const float4* wp = (const float4*)(W_sw + d * 256 + h * 64);
    const float4* ap = (const float4*)(att_dst + h * 64);
    float acc = 0.f;
#pragma unroll
    for (int c = 0; c < 16; ++c) {
        float4 wv = wp[c]; float4 av = ap[c];
        acc += wv.x * av.x + wv.y * av.y + wv.z * av.z + wv.w * av.w;
    }
    vd[d * 4 + h] = acc;
}

// ---------------------------------------------------------------------------
// CSR build: histogram -> 3-phase scan -> scatter
// ---------------------------------------------------------------------------
__global__ void __launch_bounds__(256)
k_hist(const int* __restrict__ dst, int n, int* __restrict__ hist)
{
    int e = blockIdx.x * 256 + threadIdx.x;
    if (e < n) atomicAdd(&hist[dst[e]], 1);
}

__global__ void __launch_bounds__(256)
k_scan1(const int* __restrict__ hist, int n, int* __restrict__ bsum)
{
    __shared__ int red[256];
    const int tid = threadIdx.x;
    int base = blockIdx.x * EPB + tid * 8;
    int s = 0;
#pragma unroll
    for (int i = 0; i < 8; ++i) { int idx = base + i; if (idx < n) s += hist[idx]; }
    red[tid] = s;
    __syncthreads();
    for (int off = 128; off > 0; off >>= 1) {
        if (tid < off) red[tid] += red[tid + off];
        __syncthreads();
    }
    if (tid == 0) bsum[blockIdx.x] = red[0];
}

__global__ void __launch_bounds__(256)
k_scan2(int* __restrict__ bsum, int nb)
{
    __shared__ int sh[256];
    const int tid = threadIdx.x;
    sh[tid] = (tid < nb) ? bsum[tid] : 0;
    __syncthreads();
    for (int off = 1; off < 256; off <<= 1) {
        int u = (tid >= off) ? sh[tid - off] : 0;
        __syncthreads();
        sh[tid] += u;
        __syncthreads();
    }
    if (tid < nb) bsum[tid] = (tid == 0) ? 0 : sh[tid - 1];
}

__global__ void __launch_bounds__(256)
k_scan3(const int* __restrict__ hist, int n, const int* __restrict__ bsum,
        int* __restrict__ rowptr, int* __restrict__ cursor, int total)
{
    __shared__ int tsum[256];
    const int tid = threadIdx.x;
    int base = blockIdx.x * EPB + tid * 8;
    int v[8]; int s = 0;
#pragma unroll
    for (int i = 0; i < 8; ++i) {
        int idx = base + i;
        v[i] = (idx < n) ? hist[idx] : 0;
        s += v[i];
    }
    tsum[tid] = s;
    __syncthreads();
    for (int off = 1; off < 256; off <<= 1) {
        int u = (tid >= off) ? tsum[tid - off] : 0;
        __syncthreads();
        tsum[tid] += u;
        __syncthreads();
    }
    int texcl = tsum[tid] - s;
    int run = bsum[blockIdx.x] + texcl;
#pragma unroll
    for (int i = 0; i < 8; ++i) {
        int idx = base + i;
        if (idx < n) { rowptr[idx] = run; cursor[idx] = run; run += v[i]; }
    }
    if (blockIdx.x == 0 && tid == 0) rowptr[n] = total;
}

__global__ void __launch_bounds__(256)
k_scatter(const int* __restrict__ src, const int* __restrict__ dst, int n,
          int* __restrict__ cursor, int* __restrict__ csr_src)
{
    int e = blockIdx.x * 256 + threadIdx.x;
    if (e < n) {
        int p = atomicAdd(&cursor[dst[e]], 1);
        csr_src[p] = src[e];
    }
}

// ---------------------------------------------------------------------------
// Fused GAT gather + self-loop SAGE + relu + Wg head for wells.
// 16 wells/block, 16 threads/well (thread p owns channels 4p..4p+3).
// ---------------------------------------------------------------------------
__global__ void __launch_bounds__(256)
k_gat_wells(const float* __restrict__ x_wells, const float* __restrict__ vd,
            const int* __restrict__ rowptr, const int* __restrict__ csr_src,
            const float* __restrict__ al_s, const float* __restrict__ xs,
            const float* __restrict__ Wl_ww, const float* __restrict__ Wr_ww,
            const float* __restrict__ b_sw, const float* __restrict__ bl_ww,
            const float* __restrict__ Wg, const float* __restrict__ bg,
            float* __restrict__ out)
{
    __shared__ float Wc[64][68];
    __shared__ float xw[16][68];
    __shared__ float bias[64], wg[64];
    __shared__ float vdl[256];
    const int tid = threadIdx.x;
    for (int i = tid; i < 4096; i += 256)
        Wc[i >> 6][i & 63] = Wl_ww[i] + Wr_ww[i];
    if (tid < 64) { bias[tid] = b_sw[tid] + bl_ww[tid]; wg[tid] = Wg[tid]; }
    vdl[tid] = vd[tid];
    const int base = blockIdx.x * 16;
    for (int i = tid; i < 16 * 64; i += 256) {
        int wl = i >> 6, d = i & 63;
        xw[wl][d] = x_wells[(size_t)(base + wl) * 64 + d];
    }
    __syncthreads();
    const int wl = tid >> 4, p = tid & 15;
    const int w = base + wl;
    // al_d[w,h]: 16-lane cooperative matvec + xor allreduce (all lanes get all 4)
    float h0 = 0, h1 = 0, h2 = 0, h3 = 0;
#pragma unroll
    for (int i = 0; i < 4; ++i) {
        int d = 4 * p + i;
        float xv = xw[wl][d];
        h0 += xv * vdl[d * 4 + 0];
        h1 += xv * vdl[d * 4 + 1];
        h2 += xv * vdl[d * 4 + 2];
        h3 += xv * vdl[d * 4 + 3];
    }
#pragma unroll
    for (int off = 1; off < 16; off <<= 1) {
        h0 += __shfl_xor(h0, off, 64);
        h1 += __shfl_xor(h1, off, 64);
        h2 += __shfl_xor(h2, off, 64);
        h3 += __shfl_xor(h3, off, 64);
    }
    // one-pass numerator+denominator accumulation over incoming edges
    const int r0 = rowptr[w], r1 = rowptr[w + 1];
    float den0 = 0, den1 = 0, den2 = 0, den3 = 0;
    float n0[4] = {0, 0, 0, 0}, n1[4] = {0, 0, 0, 0};
    float n2[4] = {0, 0, 0, 0}, n3[4] = {0, 0, 0, 0};
    for (int j = r0; j < r1; ++j) {
        int s = csr_src[j];
        float4 as = ((const float4*)al_s)[s];
        float e0 = __expf(lrelu02(as.x + h0));
        float e1 = __expf(lrelu02(as.y + h1));
        float e2 = __expf(lrelu02(as.z + h2));
        float e3 = __expf(lrelu02(as.w + h3));
        den0 += e0; den1 += e1; den2 += e2; den3 += e3;
        const float4* xp = (const float4*)(xs + (size_t)s * 256);
        float4 x0 = xp[p], x1 = xp[16 + p], x2 = xp[32 + p], x3 = xp[48 + p];
        n0[0] += e0 * x0.x; n0[1] += e0 * x0.y; n0[2] += e0 * x0.z; n0[3] += e0 * x0.w;
        n1[0] += e1 * x1.x; n1[1] += e1 * x1.y; n1[2] += e1 * x1.z; n1[3] += e1 * x1.w;
        n2[0] += e2 * x2.x; n2[1] += e2 * x2.y; n2[2] += e2 * x2.z; n2[3] += e2 * x2.w;
        n3[0] += e3 * x3.x; n3[1] += e3 * x3.y; n3[2] += e3 * x3.z; n3[3] += e3 * x3.w;
    }
    const int c0 = 4 * p;
    float t[4];
    if (r1 > r0) {
        float i0 = 0.25f / den0, i1 = 0.25f / den1, i2 = 0.25f / den2, i3 = 0.25f / den3;
#pragma unroll
        for (int i = 0; i < 4; ++i)
            t[i] = n0[i] * i0 + n1[i] * i1 + n2[i] * i2 + n3[i] * i3 + bias[c0 + i];
    } else {
#pragma unroll
        for (int i = 0; i < 4; ++i) t[i] = bias[c0 + i];
    }
    // + x_wells @ (Wl_ww + Wr_ww)
#pragma unroll 8
    for (int d = 0; d < 64; ++d) {
        float xv = xw[wl][d];
        float4 wv = *(const float4*)(&Wc[d][c0]);
        t[0] += xv * wv.x; t[1] += xv * wv.y; t[2] += xv * wv.z; t[3] += xv * wv.w;
    }
    float part = 0.f;
#pragma unroll
    for (int i = 0; i < 4; ++i) { float r = fmaxf(t[i], 0.f); part += r * wg[c0 + i]; }
#pragma unroll
    for (int off = 1; off < 16; off <<= 1) part += __shfl_xor(part, off, 64);
    if (p == 0) {
        float o = part + bg[0];
        out[w] = o > 0.f ? o : 0.01f * o;
    }
}

// ---------------------------------------------------------------------------
// Fused SAGE gather(mean) + self-loop GAT + relu + Wsit head for sites.
// 16 sites/block, 16 threads/site.
// ---------------------------------------------------------------------------
__global__ void __launch_bounds__(256)
k_sage_sites(const float* __restrict__ x_sites, const float* __restrict__ x_wells,
             const int* __restrict__ rowptr, const int* __restrict__ csr_src,
             const float* __restrict__ Wl_ws, const float* __restrict__ bl_ws,
             const float* __restrict__ Wr_ws, const float* __restrict__ W_ss,
             const float* __restrict__ b_ss, const float* __restrict__ Wsit,
             const float* __restrict__ bsit, float* __restrict__ out)
{
    __shared__ float Wa[64][68];
    __shared__ float Wb[64][68];
    __shared__ float xl[16][68];
    __shared__ float ml[16][68];
    __shared__ float bias[64], wsit[64];
    const int tid = threadIdx.x;
    for (int i = tid; i < 4096; i += 256) {
        int d = i >> 6, c = i & 63;
        Wa[d][c] = Wl_ws[i];
        Wb[d][c] = Wr_ws[i] + 0.25f * (W_ss[d * 256 + c] + W_ss[d * 256 + 64 + c] +
                                       W_ss[d * 256 + 128 + c] + W_ss[d * 256 + 192 + c]);
    }
    if (tid < 64) { bias[tid] = bl_ws[tid] + b_ss[tid]; wsit[tid] = Wsit[tid]; }
    const int base = blockIdx.x * 16;
    for (int i = tid; i < 16 * 64; i += 256) {
        int sl = i >> 6, d = i & 63;
        xl[sl][d] = x_sites[(size_t)(base + sl) * 64 + d];
    }
    const int sl = tid >> 4, p = tid & 15;
    const int site = base + sl;
    const int r0 = rowptr[site], r1 = rowptr[site + 1];
    float4 acc = {0.f, 0.f, 0.f, 0.f};
    for (int j = r0; j < r1; ++j) {
        int wsrc = csr_src[j];
        float4 xv = ((const float4*)(x_wells + (size_t)wsrc * 64))[p];
        acc.x += xv.x; acc.y += xv.y; acc.z += xv.z; acc.w += xv.w;
    }
    const float rc = (r1 > r0) ? 1.f / (float)(r1 - r0) : 0.f;
    acc.x *= rc; acc.y *= rc; acc.z *= rc; acc.w *= rc;
    *(float4*)(&ml[sl][4 * p]) = acc;
    __syncthreads();
    const int c0 = 4 * p;
    float t[4] = {bias[c0], bias[c0 + 1], bias[c0 + 2], bias[c0 + 3]};
#pragma unroll 4
    for (int d = 0; d < 64; ++d) {
        float mv = ml[sl][d];
        float xv = xl[sl][d];
        float4 av = *(const float4*)(&Wa[d][c0]);
        float4 bv = *(const float4*)(&Wb[d][c0]);
        t[0] += mv * av.x + xv * bv.x;
        t[1] += mv * av.y + xv * bv.y;
        t[2] += mv * av.z + xv * bv.z;
        t[3] += mv * av.w + xv * bv.w;
    }
    float part = 0.f;
#pragma unroll
    for (int i = 0; i < 4; ++i) { float r = fmaxf(t[i], 0.f); part += r * wsit[c0 + i]; }
#pragma unroll
    for (int off = 1; off < 16; off <<= 1) part += __shfl_xor(part, off, 64);
    if (p == 0) {
        float o = part + bsit[0];
        out[(size_t)NW_ + site] = o > 0.f ? o : 0.01f * o;
    }
}

// ---------------------------------------------------------------------------
extern "C" void kernel_launch(void* const* d_in, const int* in_sizes, int n_in,
                              void* d_out, int out_size, void* d_ws, size_t ws_size,
                              hipStream_t stream)
{
    const float* x_sites    = (const float*)d_in[0];
    const float* x_wells    = (const float*)d_in[1];
    const int*   e_sw_src   = (const int*)d_in[2];
    const int*   e_sw_dst   = (const int*)d_in[3];
    const int*   e_ws_src   = (const int*)d_in[4];
    const int*   e_ws_dst   = (const int*)d_in[5];
    const float* W_sw       = (const float*)d_in[6];
    const float* att_src_sw = (const float*)d_in[7];
    const float* att_dst_sw = (const float*)d_in[8];
    const float* b_sw       = (const float*)d_in[9];
    const float* Wl_ws      = (const float*)d_in[10];
    const float* bl_ws      = (const float*)d_in[11];
    const float* Wr_ws      = (const float*)d_in[12];
    const float* W_ss       = (const float*)d_in[13];
    // d_in[14], d_in[15]: att_*_ss cancel (softmax over single self edge == 1)
    const float* b_ss       = (const float*)d_in[16];
    const float* Wl_ww      = (const float*)d_in[17];
    const float* bl_ww      = (const float*)d_in[18];
    const float* Wr_ww      = (const float*)d_in[19];
    const float* Wg         = (const float*)d_in[20];
    const float* bg         = (const float*)d_in[21];
    const float* Wsit       = (const float*)d_in[22];
    const float* bsit       = (const float*)d_in[23];
    float* out = (float*)d_out;

    // workspace layout (4-byte units), everything 16B aligned
    float* ws   = (float*)d_ws;
    float* xs   = ws;                                  // NS*256
    float* al_s = xs + (size_t)NS_ * 256;              // NS*4
    float* vd   = al_s + (size_t)NS_ * 4;              // 256
    int* ip     = (int*)(vd + 256);
    int* h_sw   = ip;                                  // NW
    int* rp_sw  = h_sw + NW_;                          // NW+4 (padded)
    int* cur_sw = rp_sw + NW_ + 4;                     // NW
    int* csr_sw = cur_sw + NW_;                        // E
    int* bs_sw  = csr_sw + NE_;                        // 256
    int* h_ws   = bs_sw + 256;                         // NS
    int* rp_ws  = h_ws + NS_;                          // NS+4
    int* cur_ws = rp_ws + NS_ + 4;                     // NS
    int* csr_ws = cur_ws + NS_;                        // E
    int* bs_ws  = csr_ws + NE_;                        // 256

    hipMemsetAsync(h_sw, 0, (size_t)NW_ * sizeof(int), stream);
    hipMemsetAsync(h_ws, 0, (size_t)NS_ * sizeof(int), stream);

    const int egrid = (NE_ + 255) / 256;
    const int nb_sw = (NW_ + EPB - 1) / EPB;   // 196
    const int nb_ws = (NS_ + EPB - 1) / EPB;   // 49

    // CSR build for both relations
    hipLaunchKernelGGL(k_hist, dim3(egrid), dim3(256), 0, stream, e_sw_dst, NE_, h_sw);
    hipLaunchKernelGGL(k_hist, dim3(egrid), dim3(256), 0, stream, e_ws_dst, NE_, h_ws);
    hipLaunchKernelGGL(k_scan1, dim3(nb_sw), dim3(256), 0, stream, h_sw, NW_, bs_sw);
    hipLaunchKernelGGL(k_scan1, dim3(nb_ws), dim3(256), 0, stream, h_ws, NS_, bs_ws);
    hipLaunchKernelGGL(k_scan2, dim3(1), dim3(256), 0, stream, bs_sw, nb_sw);
    hipLaunchKernelGGL(k_scan2, dim3(1), dim3(256), 0, stream, bs_ws, nb_ws);
    hipLaunchKernelGGL(k_scan3, dim3(nb_sw), dim3(256), 0, stream, h_sw, NW_, bs_sw, rp_sw, cur_sw, NE_);
    hipLaunchKernelGGL(k_scan3, dim3(nb_ws), dim3(256), 0, stream, h_ws, NS_, bs_ws, rp_ws, cur_ws, NE_);
    hipLaunchKernelGGL(k_scatter, dim3(egrid), dim3(256), 0, stream, e_sw_src, e_sw_dst, NE_, cur_sw, csr_sw);
    hipLaunchKernelGGL(k_scatter, dim3(egrid), dim3(256), 0, stream, e_ws_src, e_ws_dst, NE_, cur_ws, csr_ws);

    // dense precompute
    hipLaunchKernelGGL(k_vd, dim3(1), dim3(256), 0, stream, W_sw, att_dst_sw, vd);
    hipLaunchKernelGGL(k_sites_pre, dim3(NS_ / 32), dim3(256), 0, stream,
                       x_sites, W_sw, att_src_sw, xs, al_s);

    // fused gather + epilogues
    hipLaunchKernelGGL(k_gat_wells, dim3(NW_ / 16), dim3(256), 0, stream,
                       x_wells, vd, rp_sw, csr_sw, al_s, xs,
                       Wl_ww, Wr_ww, b_sw, bl_ww, Wg, bg, out);
    hipLaunchKernelGGL(k_sage_sites, dim3(NS_ / 16), dim3(256), 0, stream,
                       x_sites, x_wells, rp_ws, csr_ws,
                       Wl_ws, bl_ws, Wr_ws, W_ss, b_ss, Wsit, bsit, out);
}